// Round 8
// baseline (87.846 us; speedup 1.0000x reference)
//
#include <hip/hip_runtime.h>
#include <hip/hip_cooperative_groups.h>
#include <math.h>

namespace cg = cooperative_groups;

#define EPSF 1e-7f
#define NP 4096

typedef __attribute__((ext_vector_type(8)))  short  short8;
typedef __attribute__((ext_vector_type(8)))  __bf16 bf16x8;
typedef __attribute__((ext_vector_type(16))) float  f32x16;

__device__ __forceinline__ unsigned short bf16_rn(float x) {
    unsigned int u = __float_as_uint(x);
    unsigned int r = u + 0x7FFFu + ((u >> 16) & 1u);
    return (unsigned short)(r >> 16);
}
__device__ __forceinline__ float bf16_to_f(unsigned short h) {
    return __uint_as_float(((unsigned int)h) << 16);
}

// fold 16 mfma outputs into 2 running-min accumulators (8 v_min3_f32)
__device__ __forceinline__ void fold16(const f32x16& d, float& ra, float& rb) {
    ra = fminf(fminf(d[0],  d[1]),  ra);
    rb = fminf(fminf(d[2],  d[3]),  rb);
    ra = fminf(fminf(d[4],  d[5]),  ra);
    rb = fminf(fminf(d[6],  d[7]),  rb);
    ra = fminf(fminf(d[8],  d[9]),  ra);
    rb = fminf(fminf(d[10], d[11]), rb);
    ra = fminf(fminf(d[12], d[13]), ra);
    rb = fminf(fminf(d[14], d[15]), rb);
}

// query-side (B operand) fragment (verified rounds 4-7, absmax 0.0):
// kg=0 -> [-2xh,-2yh,-2zh,-2xl,-2yl,-2zl,-2xh,-2yh] ; kg=1 -> [-2zh,1,1,0..]
__device__ __forceinline__ bf16x8 make_qfrag(float x, float y, float z, int kg) {
    float m2x = -2.f * x, m2y = -2.f * y, m2z = -2.f * z;
    unsigned short xh = bf16_rn(m2x), yh = bf16_rn(m2y), zh = bf16_rn(m2z);
    unsigned short xl = bf16_rn(m2x - bf16_to_f(xh));
    unsigned short yl = bf16_rn(m2y - bf16_to_f(yh));
    unsigned short zl = bf16_rn(m2z - bf16_to_f(zh));
    short8 s;
    if (kg == 0)
        s = short8{(short)xh,(short)yh,(short)zh,(short)xl,(short)yl,(short)zl,(short)xh,(short)yh};
    else
        s = short8{(short)zh,(short)0x3F80,(short)0x3F80,0,0,0,0,0};
    return __builtin_bit_cast(bf16x8, s);
}

// ---------------------------------------------------------------------------
// Single fused kernel (cooperative): 256 blocks x 512 threads, 1 block/CU.
// Phase 1 (r6 structure + software-pipelined fold): block builds the full
// 4096-pt db panel of its (dir,b) in LDS (split-bf16 A-frag layout); waves
// 0-3 scan half 0, waves 4-7 half 1, 2 query B-frags per wave; per tile
// 1 ds_read_b128 + 2 MFMA, fold of tile t overlaps MFMAs of tile t+1.
// Per-query min merged through LDS, sqrt, block sum -> parts[bid].
// grid.sync(), then block 0 computes BCE + CR + sum(parts) -> out[0].
// Deterministic: fixed-order sums, no atomics.
// ---------------------------------------------------------------------------
__global__ __launch_bounds__(512) void vae_fused(
    const float* __restrict__ pred, const float* __restrict__ targ,
    const float* __restrict__ prob_pred, const float* __restrict__ prob_target,
    const float* __restrict__ mu, const float* __restrict__ lb,
    const float* __restrict__ ub, float* __restrict__ out,
    float* __restrict__ parts, int nprob, int K)
{
    __shared__ char  panel[131072];        // 4096 pts x 32B (128 tiles x 1KB)
    __shared__ float redbuf[512];
    __shared__ float red4[4];
    __shared__ float s1[8], s2[8];

    const int tid  = threadIdx.x;
    const int lane = tid & 63, w = tid >> 6, kg = lane >> 5;
    const int half = w >> 2;               // db half this wave scans
    const int bid  = blockIdx.x;
    const int strip = bid & 15;            // 256-query strip
    const int combo = bid >> 4;            // dir*8 + b
    const int dir = combo >> 3, b = combo & 7;

    // ---- query (B operand) fragments + fp32 norms
    const float* Q = (dir ? targ : pred) + (size_t)b * NP * 3;
    const int qA = strip * 256 + (w & 3) * 64 + (lane & 31);
    const int qB = qA + 32;
    const float ax = Q[qA * 3], ay = Q[qA * 3 + 1], az = Q[qA * 3 + 2];
    const float bx = Q[qB * 3], by = Q[qB * 3 + 1], bz = Q[qB * 3 + 2];
    const bf16x8 fragA = make_qfrag(ax, ay, az, kg);
    const bf16x8 fragB = make_qfrag(bx, by, bz, kg);
    const float n1A = fmaf(ax, ax, fmaf(ay, ay, az * az));
    const float n1B = fmaf(bx, bx, fmaf(by, by, bz * bz));

    // ---- build full 4096-point panel in LDS (8 pts/thread)
    const float* D = (dir ? pred : targ) + (size_t)b * NP * 3;
#pragma unroll
    for (int i = 0; i < 8; ++i) {
        const int pt = i * 512 + tid;      // 0..4095
        const float* dp = D + (size_t)pt * 3;
        float x = dp[0], y = dp[1], z = dp[2];
        float n2 = fmaf(x, x, fmaf(y, y, z * z));
        unsigned short xh = bf16_rn(x), yh = bf16_rn(y), zh = bf16_rn(z);
        unsigned short xl = bf16_rn(x - bf16_to_f(xh));
        unsigned short yl = bf16_rn(y - bf16_to_f(yh));
        unsigned short zl = bf16_rn(z - bf16_to_f(zh));
        unsigned short nh = bf16_rn(n2);
        unsigned short nl = bf16_rn(n2 - bf16_to_f(nh));
        short8 k0 = short8{(short)xh,(short)yh,(short)zh,
                           (short)xh,(short)yh,(short)zh,
                           (short)xl,(short)yl};
        short8 k1 = short8{(short)zl,(short)nh,(short)nl,0,0,0,0,0};
        char* base = panel + (pt >> 5) * 1024 + (pt & 31) * 16;
        *(short8*)base         = k0;
        *(short8*)(base + 512) = k1;
    }
    __syncthreads();

    // ---- 64 MFMA tiles, software-pipelined: fold(t) overlaps mfma(t+1)
    float rA0 = 3.4e38f, rA1 = 3.4e38f, rB0 = 3.4e38f, rB1 = 3.4e38f;
    const f32x16 zero = {0.f};
    const char* abase = panel + (size_t)half * 65536 + kg * 512 + (lane & 31) * 16;

    bf16x8 af = *(const bf16x8*)abase;
    f32x16 c0 = __builtin_amdgcn_mfma_f32_32x32x16_bf16(af, fragA, zero, 0, 0, 0);
    f32x16 c1 = __builtin_amdgcn_mfma_f32_32x32x16_bf16(af, fragB, zero, 0, 0, 0);
#pragma unroll 3
    for (int t = 1; t < 64; ++t) {
        bf16x8 af2 = *(const bf16x8*)(abase + t * 1024);
        f32x16 n0 = __builtin_amdgcn_mfma_f32_32x32x16_bf16(af2, fragA, zero, 0, 0, 0);
        f32x16 n1 = __builtin_amdgcn_mfma_f32_32x32x16_bf16(af2, fragB, zero, 0, 0, 0);
        fold16(c0, rA0, rA1);
        fold16(c1, rB0, rB1);
        c0 = n0; c1 = n1;
    }
    fold16(c0, rA0, rA1);
    fold16(c1, rB0, rB1);

    // ---- merge C-row halves, add |q|^2, exchange halves through LDS
    float rA = fminf(rA0, rA1);  rA = fminf(rA, __shfl_xor(rA, 32));
    float rB = fminf(rB0, rB1);  rB = fminf(rB, __shfl_xor(rB, 32));
    float val = (lane < 32) ? (rA + n1A) : (rB + n1B);
    __syncthreads();                       // panel reads done
    redbuf[half * 256 + (w & 3) * 64 + lane] = val;
    __syncthreads();

    // ---- min over halves, sqrt, deterministic block sum
    if (tid < 256) {
        float m = fminf(redbuf[tid], redbuf[256 + tid]);
        float dist = sqrtf(fmaxf(m, 1e-12f));
        for (int off = 32; off; off >>= 1) dist += __shfl_xor(dist, off);
        if ((tid & 63) == 0) red4[tid >> 6] = dist;
    }
    __syncthreads();
    if (tid == 0)
        parts[bid] = red4[0] + red4[1] + red4[2] + red4[3];

    __threadfence();
    cg::this_grid().sync();

    // ---- finalize on block 0: BCE + CR + sum(parts) -> scalar
    if (bid != 0) return;
    __threadfence();

    float bce = 0.f;
    const float pmax = 1.0f - EPSF;
    for (int i = tid; i < nprob; i += 512) {
        float p = prob_pred[i];
        p = fminf(fmaxf(p, EPSF), pmax);
        float t = prob_target[i];
        bce += t * logf(p) + (1.0f - t) * log1pf(-p);
    }

    float cr = 0.f;
    const float invK = 1.0f / (float)K;
    for (int i = tid; i < K; i += 512) {
        float c = fabsf(mu[i]) - 0.5f * (lb[i] + ub[i]) + invK;
        cr += fmaxf(c, 0.f);
    }

    float v1 = (tid < 256 ? parts[tid] : 0.f) + cr;
    float v2 = bce;
    for (int off = 32; off; off >>= 1) {
        v1 += __shfl_xor(v1, off);
        v2 += __shfl_xor(v2, off);
    }
    if (lane == 0) { s1[w] = v1; s2[w] = v2; }
    __syncthreads();
    if (tid == 0) {
        float V1 = 0.f, V2 = 0.f;
#pragma unroll
        for (int i = 0; i < 8; ++i) { V1 += s1[i]; V2 += s2[i]; }
        out[0] = V1 - V2 / (float)nprob;
    }
}

extern "C" void kernel_launch(void* const* d_in, const int* in_sizes, int n_in,
                              void* d_out, int out_size, void* d_ws, size_t ws_size,
                              hipStream_t stream) {
    const float* prob_pred   = (const float*)d_in[0];
    const float* prob_target = (const float*)d_in[1];
    const float* x_pred      = (const float*)d_in[2];
    const float* x_target    = (const float*)d_in[3];
    const float* mu          = (const float*)d_in[4];
    const float* lb          = (const float*)d_in[5];
    const float* ub          = (const float*)d_in[6];
    float* out   = (float*)d_out;
    float* parts = (float*)d_ws;           // 256 floats

    int nprob = in_sizes[0];                // 8000
    int K     = in_sizes[4];                // 1000

    void* args[] = {
        (void*)&x_pred, (void*)&x_target,
        (void*)&prob_pred, (void*)&prob_target,
        (void*)&mu, (void*)&lb, (void*)&ub,
        (void*)&out, (void*)&parts,
        (void*)&nprob, (void*)&K
    };
    hipLaunchCooperativeKernel((const void*)vae_fused,
                               dim3(256), dim3(512), args, 0, stream);
}

// Round 9
// 28.676 us; speedup vs baseline: 3.0634x; 3.0634x over previous
//
#include <hip/hip_runtime.h>
#include <math.h>

#define EPSF 1e-7f
#define NP 4096

typedef __attribute__((ext_vector_type(8)))  short  short8;
typedef __attribute__((ext_vector_type(8)))  __bf16 bf16x8;
typedef __attribute__((ext_vector_type(16))) float  f32x16;

__device__ __forceinline__ unsigned short bf16_rn(float x) {
    unsigned int u = __float_as_uint(x);
    unsigned int r = u + 0x7FFFu + ((u >> 16) & 1u);
    return (unsigned short)(r >> 16);
}
__device__ __forceinline__ float bf16_to_f(unsigned short h) {
    return __uint_as_float(((unsigned int)h) << 16);
}

// fold 16 mfma outputs into 2 running-min accumulators (8 v_min3_f32)
__device__ __forceinline__ void fold16(const f32x16& d, float& ra, float& rb) {
    ra = fminf(fminf(d[0],  d[1]),  ra);
    rb = fminf(fminf(d[2],  d[3]),  rb);
    ra = fminf(fminf(d[4],  d[5]),  ra);
    rb = fminf(fminf(d[6],  d[7]),  rb);
    ra = fminf(fminf(d[8],  d[9]),  ra);
    rb = fminf(fminf(d[10], d[11]), rb);
    ra = fminf(fminf(d[12], d[13]), ra);
    rb = fminf(fminf(d[14], d[15]), rb);
}

// query-side (B operand) fragment (verified rounds 4-8, absmax 0.0):
// kg=0 -> [-2xh,-2yh,-2zh,-2xl,-2yl,-2zl,-2xh,-2yh] ; kg=1 -> [-2zh,1,1,0..]
__device__ __forceinline__ bf16x8 make_qfrag(float x, float y, float z, int kg) {
    float m2x = -2.f * x, m2y = -2.f * y, m2z = -2.f * z;
    unsigned short xh = bf16_rn(m2x), yh = bf16_rn(m2y), zh = bf16_rn(m2z);
    unsigned short xl = bf16_rn(m2x - bf16_to_f(xh));
    unsigned short yl = bf16_rn(m2y - bf16_to_f(yh));
    unsigned short zl = bf16_rn(m2z - bf16_to_f(zh));
    short8 s;
    if (kg == 0)
        s = short8{(short)xh,(short)yh,(short)zh,(short)xl,(short)yl,(short)zl,(short)xh,(short)yh};
    else
        s = short8{(short)zh,(short)0x3F80,(short)0x3F80,0,0,0,0,0};
    return __builtin_bit_cast(bf16x8, s);
}

// ---------------------------------------------------------------------------
// Fused chamfer (r6 shell, dual-slack pipelined loop): grid (16 strips,
// 16 combos) = 256 blocks (1/CU), 512 threads (8 waves), ~131KB LDS.
// Block builds the full 4096-pt db panel of its (dir,b) in LDS once
// (split-bf16 A-frag layout). Waves 0-3 scan half 0, waves 4-7 half 1, each
// wave holds 2 query B-frags (64 queries). 2-tile loop body with BOTH
// latencies covered: ds_read of tiles t+2,t+3 issued one body before use;
// MFMA results of tiles t-2,t-1 folded one body after issue (even/odd
// streams). Min order-independent -> bit-identical result.
// ---------------------------------------------------------------------------
__global__ __launch_bounds__(512) void chamfer_fused(
    const float* __restrict__ pred, const float* __restrict__ targ,
    float* __restrict__ parts)
{
    const int tid  = threadIdx.x;
    const int lane = tid & 63, w = tid >> 6, kg = lane >> 5;
    const int half = w >> 2;               // db half this wave scans
    const int strip = blockIdx.x;          // 0..15 : 256-query strip
    const int combo = blockIdx.y;          // 0..15 : dir*8 + b
    const int dir = combo >> 3, b = combo & 7;

    __shared__ char  panel[131072];        // 4096 pts x 32B (128 tiles x 1KB)
    __shared__ float redbuf[512];
    __shared__ float red4[4];

    // ---- query (B operand) fragments + fp32 norms
    const float* Q = (dir ? targ : pred) + (size_t)b * NP * 3;
    const int qA = strip * 256 + (w & 3) * 64 + (lane & 31);
    const int qB = qA + 32;
    const float ax = Q[qA * 3], ay = Q[qA * 3 + 1], az = Q[qA * 3 + 2];
    const float bx = Q[qB * 3], by = Q[qB * 3 + 1], bz = Q[qB * 3 + 2];
    const bf16x8 fragA = make_qfrag(ax, ay, az, kg);
    const bf16x8 fragB = make_qfrag(bx, by, bz, kg);
    const float n1A = fmaf(ax, ax, fmaf(ay, ay, az * az));
    const float n1B = fmaf(bx, bx, fmaf(by, by, bz * bz));

    // ---- build full 4096-point panel in LDS (8 pts/thread)
    const float* D = (dir ? pred : targ) + (size_t)b * NP * 3;
#pragma unroll
    for (int i = 0; i < 8; ++i) {
        const int pt = i * 512 + tid;      // 0..4095
        const float* dp = D + (size_t)pt * 3;
        float x = dp[0], y = dp[1], z = dp[2];
        float n2 = fmaf(x, x, fmaf(y, y, z * z));
        unsigned short xh = bf16_rn(x), yh = bf16_rn(y), zh = bf16_rn(z);
        unsigned short xl = bf16_rn(x - bf16_to_f(xh));
        unsigned short yl = bf16_rn(y - bf16_to_f(yh));
        unsigned short zl = bf16_rn(z - bf16_to_f(zh));
        unsigned short nh = bf16_rn(n2);
        unsigned short nl = bf16_rn(n2 - bf16_to_f(nh));
        short8 k0 = short8{(short)xh,(short)yh,(short)zh,
                           (short)xh,(short)yh,(short)zh,
                           (short)xl,(short)yl};
        short8 k1 = short8{(short)zl,(short)nh,(short)nl,0,0,0,0,0};
        char* base = panel + (pt >> 5) * 1024 + (pt & 31) * 16;
        *(short8*)base         = k0;
        *(short8*)(base + 512) = k1;
    }
    __syncthreads();

    // ---- 64 MFMA tiles, dual-slack software pipeline
    float rA0 = 3.4e38f, rA1 = 3.4e38f, rB0 = 3.4e38f, rB1 = 3.4e38f;
    const f32x16 zero = {0.f};
    const char* ab = panel + (size_t)half * 65536 + kg * 512 + (lane & 31) * 16;

    bf16x8 a0 = *(const bf16x8*)(ab);
    bf16x8 a1 = *(const bf16x8*)(ab + 1024);
    f32x16 e0 = __builtin_amdgcn_mfma_f32_32x32x16_bf16(a0, fragA, zero, 0, 0, 0);
    f32x16 e1 = __builtin_amdgcn_mfma_f32_32x32x16_bf16(a0, fragB, zero, 0, 0, 0);
    f32x16 o0 = __builtin_amdgcn_mfma_f32_32x32x16_bf16(a1, fragA, zero, 0, 0, 0);
    f32x16 o1 = __builtin_amdgcn_mfma_f32_32x32x16_bf16(a1, fragB, zero, 0, 0, 0);
    bf16x8 a2 = *(const bf16x8*)(ab + 2048);
    bf16x8 a3 = *(const bf16x8*)(ab + 3072);

#pragma unroll 2
    for (int t = 2; t <= 60; t += 2) {
        // prefetch tiles t+2, t+3 (consumed next body: >= 1 body of slack)
        bf16x8 a2n = *(const bf16x8*)(ab + (t + 2) * 1024);
        bf16x8 a3n = *(const bf16x8*)(ab + (t + 3) * 1024);
        // fold tile t-2 (even stream; issued one body ago)
        fold16(e0, rA0, rA1);
        fold16(e1, rB0, rB1);
        e0 = __builtin_amdgcn_mfma_f32_32x32x16_bf16(a2, fragA, zero, 0, 0, 0);
        e1 = __builtin_amdgcn_mfma_f32_32x32x16_bf16(a2, fragB, zero, 0, 0, 0);
        // fold tile t-1 (odd stream)
        fold16(o0, rA0, rA1);
        fold16(o1, rB0, rB1);
        o0 = __builtin_amdgcn_mfma_f32_32x32x16_bf16(a3, fragA, zero, 0, 0, 0);
        o1 = __builtin_amdgcn_mfma_f32_32x32x16_bf16(a3, fragB, zero, 0, 0, 0);
        a2 = a2n; a3 = a3n;
    }
    // epilogue: pending folds for tiles 60,61; compute + fold tiles 62,63
    fold16(e0, rA0, rA1);
    fold16(e1, rB0, rB1);
    e0 = __builtin_amdgcn_mfma_f32_32x32x16_bf16(a2, fragA, zero, 0, 0, 0);
    e1 = __builtin_amdgcn_mfma_f32_32x32x16_bf16(a2, fragB, zero, 0, 0, 0);
    fold16(o0, rA0, rA1);
    fold16(o1, rB0, rB1);
    o0 = __builtin_amdgcn_mfma_f32_32x32x16_bf16(a3, fragA, zero, 0, 0, 0);
    o1 = __builtin_amdgcn_mfma_f32_32x32x16_bf16(a3, fragB, zero, 0, 0, 0);
    fold16(e0, rA0, rA1);
    fold16(e1, rB0, rB1);
    fold16(o0, rA0, rA1);
    fold16(o1, rB0, rB1);

    // ---- merge C-row halves, add |q|^2, exchange halves through LDS
    float rA = fminf(rA0, rA1);  rA = fminf(rA, __shfl_xor(rA, 32));
    float rB = fminf(rB0, rB1);  rB = fminf(rB, __shfl_xor(rB, 32));
    float val = (lane < 32) ? (rA + n1A) : (rB + n1B);
    __syncthreads();                       // panel reads done
    redbuf[half * 256 + (w & 3) * 64 + lane] = val;
    __syncthreads();

    // ---- min over halves, sqrt, deterministic block sum
    if (tid < 256) {
        float m = fminf(redbuf[tid], redbuf[256 + tid]);
        float dist = sqrtf(fmaxf(m, 1e-12f));
        for (int off = 32; off; off >>= 1) dist += __shfl_xor(dist, off);
        if ((tid & 63) == 0) red4[tid >> 6] = dist;
    }
    __syncthreads();
    if (tid == 0)
        parts[blockIdx.y * 16 + blockIdx.x] = red4[0] + red4[1] + red4[2] + red4[3];
}

// ---------------------------------------------------------------------------
// Finalize: sum 256 chamfer partials + BCE + CR -> scalar.
// ---------------------------------------------------------------------------
__global__ __launch_bounds__(256) void finalize_kernel(
    const float* __restrict__ parts,
    const float* __restrict__ prob_pred, const float* __restrict__ prob_target,
    const float* __restrict__ mu, const float* __restrict__ lb,
    const float* __restrict__ ub,
    float* __restrict__ out, int nprob, int K)
{
    const int tid = threadIdx.x;

    float bce = 0.f;
    const float pmax = 1.0f - EPSF;
    for (int i = tid; i < nprob; i += 256) {
        float p = prob_pred[i];
        p = fminf(fmaxf(p, EPSF), pmax);
        float t = prob_target[i];
        bce += t * logf(p) + (1.0f - t) * log1pf(-p);
    }

    float cr = 0.f;
    const float invK = 1.0f / (float)K;
    for (int i = tid; i < K; i += 256) {
        float c = fabsf(mu[i]) - 0.5f * (lb[i] + ub[i]) + invK;
        cr += fmaxf(c, 0.f);
    }

    float v1 = parts[tid] + cr;
    float v2 = bce;
    for (int off = 32; off; off >>= 1) {
        v1 += __shfl_xor(v1, off);
        v2 += __shfl_xor(v2, off);
    }
    __shared__ float s1[4], s2[4];
    if ((tid & 63) == 0) { s1[tid >> 6] = v1; s2[tid >> 6] = v2; }
    __syncthreads();
    if (tid == 0) {
        float V1 = s1[0] + s1[1] + s1[2] + s1[3];
        float V2 = s2[0] + s2[1] + s2[2] + s2[3];
        out[0] = V1 - V2 / (float)nprob;
    }
}

extern "C" void kernel_launch(void* const* d_in, const int* in_sizes, int n_in,
                              void* d_out, int out_size, void* d_ws, size_t ws_size,
                              hipStream_t stream) {
    const float* prob_pred   = (const float*)d_in[0];
    const float* prob_target = (const float*)d_in[1];
    const float* x_pred      = (const float*)d_in[2];
    const float* x_target    = (const float*)d_in[3];
    const float* mu          = (const float*)d_in[4];
    const float* lb          = (const float*)d_in[5];
    const float* ub          = (const float*)d_in[6];
    float* out   = (float*)d_out;
    float* parts = (float*)d_ws;          // 256 floats

    const int K     = in_sizes[4];        // 1000
    const int nprob = in_sizes[0];        // 8000

    dim3 grid(16, 16);
    chamfer_fused<<<grid, 512, 0, stream>>>(x_pred, x_target, parts);
    finalize_kernel<<<1, 256, 0, stream>>>(parts, prob_pred, prob_target,
                                           mu, lb, ub, out, nprob, K);
}